// Round 2
// baseline (40623.584 us; speedup 1.0000x reference)
//
#include <hip/hip_runtime.h>

#define TT 16384
#define HID 256
#define EMBD 16
#define TMPD 128
#define VOC 2048
#define NG 8
#define RPW (VOC / NG)   // 256 rows per workgroup

typedef unsigned long long u64;
typedef unsigned int u32;
typedef unsigned short u16;

// workspace layout (bytes)
#define U_OFF_B    0ull                      // 16384*128*4 = 8 MiB
#define C_OFF_B    8388608ull                // 2048*128*4  = 1 MiB
#define SLOT_OFF_B 9437184ull                // 16384*16*8  = 2 MiB (2 u64 per wg per step)

#define TAG_A 0xBEEFull
#define TAG_B 0x0000C0DEull

// ---------------------------------------------------------------------------
// Phase A: U[t] = b1 + W1[:, :256] @ x_t   (blocks 0..TT-1)
//          C[i] = W1[:, 256:272] @ emb[i]  (blocks TT..TT+VOC-1)
// Also initializes every per-step slot to an invalid sentinel.
// ---------------------------------------------------------------------------
__global__ __launch_bounds__(128) void prep_kernel(
    const float* __restrict__ x, const float* __restrict__ emb,
    const float* __restrict__ W1, const float* __restrict__ b1,
    float* __restrict__ U, float* __restrict__ C, u64* __restrict__ slots)
{
  const int b = blockIdx.x;
  const int j = threadIdx.x;   // 0..127 = output feature
  if (b < TT) {
    __shared__ __align__(16) float xs[HID];
    if (j < HID / 4) ((float4*)xs)[j] = ((const float4*)(x + (size_t)b * HID))[j];
    if (j < 2 * NG) slots[(size_t)b * 2 * NG + j] = ~0ull;   // invalid sentinel
    __syncthreads();
    float acc = b1[j];
    const float4* wr = (const float4*)(W1 + (size_t)j * (HID + EMBD)); // 1088B rows, 16B aligned
    #pragma unroll 8
    for (int c = 0; c < HID / 4; ++c) {
      float4 w = wr[c];
      acc = fmaf(xs[4 * c + 0], w.x, acc);
      acc = fmaf(xs[4 * c + 1], w.y, acc);
      acc = fmaf(xs[4 * c + 2], w.z, acc);
      acc = fmaf(xs[4 * c + 3], w.w, acc);
    }
    U[(size_t)b * TMPD + j] = acc;
  } else {
    const int e = b - TT;
    const float* er = emb + (size_t)e * EMBD;
    const float* wr = W1 + (size_t)j * (HID + EMBD) + HID;
    float acc = 0.f;
    #pragma unroll
    for (int k = 0; k < EMBD; ++k) acc = fmaf(er[k], wr[k], acc);
    C[(size_t)e * TMPD + j] = acc;
  }
}

// ---------------------------------------------------------------------------
// Phase B: 8 persistent workgroups, register-resident W2 shard (256 rows each).
// Per step: h = lrelu(U[t] + C[idx]); partial logits; publish two u64 slots:
//   slotA = ord(maxlogit)<<32 | (2047-argmaxrow)<<16 | 0xBEEF
//   slotB = f32bits(partial sumexp)<<32 | 0x0000C0DE
// u64-max over slotA keys gives global argmax with first-index tie-break;
// fp32 partial sums give an exact logsumexp. Spin until all 16 slots carry
// their magic tags (0xAA poison and ~0 sentinel both fail).
// ---------------------------------------------------------------------------
__global__ __launch_bounds__(256, 1) void seq_kernel(
    const float* __restrict__ emb, const float* __restrict__ W2,
    const float* __restrict__ b2v, const int* __restrict__ init_idx,
    const float* __restrict__ U, const float* __restrict__ C,
    u64* slots,
    float* __restrict__ out0, float* __restrict__ out1,
    float* __restrict__ out2)
{
  const int g = blockIdx.x;
  const int tid = threadIdx.x;
  const int row = g * RPW + tid;

  // W2 row -> 128 VGPRs (fp32)
  float w[TMPD];
  {
    const float4* wr = (const float4*)(W2 + (size_t)row * TMPD); // 512B rows, aligned
    #pragma unroll
    for (int c = 0; c < TMPD / 4; ++c) {
      float4 v = wr[c];
      w[4 * c + 0] = v.x; w[4 * c + 1] = v.y; w[4 * c + 2] = v.z; w[4 * c + 3] = v.w;
    }
  }
  const float br = b2v[row];

  __shared__ __align__(16) float hbuf[TMPD];
  __shared__ u64 wk[4];
  __shared__ float wsum[4];
  __shared__ int bc_idx;
  __shared__ float bc_logS;

  int cur = init_idx[0];

  for (int t = 0; t < TT; ++t) {
    if (tid < TMPD) {
      float v = U[(size_t)t * TMPD + tid] + C[(size_t)cur * TMPD + tid];
      hbuf[tid] = (v > 0.f) ? v : 0.01f * v;
    }
    __syncthreads();                                   // sync#1

    float acc = br;
    #pragma unroll
    for (int k0 = 0; k0 < TMPD; k0 += 4) {
      float4 hv = *(const float4*)(hbuf + k0);         // LDS broadcast b128
      acc = fmaf(w[k0 + 0], hv.x, acc);
      acc = fmaf(w[k0 + 1], hv.y, acc);
      acc = fmaf(w[k0 + 2], hv.z, acc);
      acc = fmaf(w[k0 + 3], hv.w, acc);
    }
    float s = __expf(acc);

    u32 fb  = __float_as_uint(acc);
    u32 ord = (fb & 0x80000000u) ? ~fb : (fb | 0x80000000u);
    u64 kk  = ((u64)ord << 32) | ((u64)(u32)(2047 - row) << 16) | TAG_A;

    #pragma unroll
    for (int off = 32; off > 0; off >>= 1) {           // wave64 down-reduce
      u64 ok = __shfl_down(kk, off);
      float os = __shfl_down(s, off);
      s += os;
      if (ok > kk) kk = ok;
    }
    if ((tid & 63) == 0) { wk[tid >> 6] = kk; wsum[tid >> 6] = s; }
    __syncthreads();                                   // sync#2

    if (tid == 0) {
      u64 K = wk[0]; float S = wsum[0];
      #pragma unroll
      for (int q = 1; q < 4; ++q) { if (wk[q] > K) K = wk[q]; S += wsum[q]; }
      u64* base = slots + (size_t)t * 2 * NG;
      u64 keyB = ((u64)__float_as_uint(S) << 32) | TAG_B;
      __hip_atomic_store(base + 2 * g + 0, K,    __ATOMIC_RELAXED, __HIP_MEMORY_SCOPE_AGENT);
      __hip_atomic_store(base + 2 * g + 1, keyB, __ATOMIC_RELAXED, __HIP_MEMORY_SCOPE_AGENT);

      u64 ka[NG], kb[NG];
      for (;;) {
        bool okall = true;
        #pragma unroll
        for (int q = 0; q < NG; ++q) {
          ka[q] = __hip_atomic_load(base + 2 * q + 0, __ATOMIC_RELAXED, __HIP_MEMORY_SCOPE_AGENT);
          kb[q] = __hip_atomic_load(base + 2 * q + 1, __ATOMIC_RELAXED, __HIP_MEMORY_SCOPE_AGENT);
          okall &= ((ka[q] & 0xFFFFull) == TAG_A) & (((ka[q] >> 16) & 0xFFFFull) <= 2047ull);
          okall &= ((kb[q] & 0xFFFFFFFFull) == TAG_B);
        }
        if (okall) break;
      }
      u64 best = ka[0];
      float St = __uint_as_float((u32)(kb[0] >> 32));
      #pragma unroll
      for (int q = 1; q < NG; ++q) {
        St += __uint_as_float((u32)(kb[q] >> 32));
        if (ka[q] > best) best = ka[q];
      }
      bc_idx  = 2047 - (int)((best >> 16) & 0xFFFFull);
      bc_logS = __logf(St);
    }
    __syncthreads();                                   // sync#3

    const int nidx = bc_idx;
    const float lgS = bc_logS;
    out0[(size_t)t * VOC + row] = acc - lgS;
    if (g == 0) {
      if (tid < EMBD) out1[(size_t)t * EMBD + tid] = emb[(size_t)nidx * EMBD + tid];
      if (tid == 0)   out2[t] = (float)nidx;
    }
    cur = nidx;
  }
}

// ---------------------------------------------------------------------------
extern "C" void kernel_launch(void* const* d_in, const int* in_sizes, int n_in,
                              void* d_out, int out_size, void* d_ws, size_t ws_size,
                              hipStream_t stream) {
  const float* x    = (const float*)d_in[0];   // [16384,256] f32
  const float* emb  = (const float*)d_in[1];   // [2048,16]   f32
  const float* W1   = (const float*)d_in[2];   // [128,272]   f32
  const float* b1   = (const float*)d_in[3];   // [128]       f32
  const float* W2   = (const float*)d_in[4];   // [2048,128]  f32
  const float* b2v  = (const float*)d_in[5];   // [2048]      f32
  const int*   init = (const int*)d_in[6];     // scalar int

  float* U    = (float*)((char*)d_ws + U_OFF_B);
  float* C    = (float*)((char*)d_ws + C_OFF_B);
  u64*   slot = (u64*)((char*)d_ws + SLOT_OFF_B);

  float* out0 = (float*)d_out;                                   // [T, 2048]
  float* out1 = (float*)d_out + (size_t)TT * VOC;                // [T, 1, 16]
  float* out2 = (float*)d_out + (size_t)TT * VOC + (size_t)TT * EMBD; // [T]

  hipLaunchKernelGGL(prep_kernel, dim3(TT + VOC), dim3(128), 0, stream,
                     x, emb, W1, b1, U, C, slot);
  hipLaunchKernelGGL(seq_kernel, dim3(NG), dim3(256), 0, stream,
                     emb, W2, b2v, init, U, C, slot, out0, out1, out2);
}